// Round 14
// baseline (930.941 us; speedup 1.0000x reference)
//
#include <hip/hip_runtime.h>

#define NB 64
#define NN 128
#define ND 2048

// ---------------------------------------------------------------------------
// Kernel A: cost[b][i][j] = sqrt(max(||x_i||^2 + ||y_j||^2 - 2 x_i.y_j, 0))
// (round-9 validated version — 256 blocks, 32-row x 128-col tiles)
// ---------------------------------------------------------------------------
__global__ __launch_bounds__(256) void cost_kernel(const float* __restrict__ X,
                                                   const float* __restrict__ Y,
                                                   float* __restrict__ cost) {
  const int b  = blockIdx.x >> 2;
  const int rt = blockIdx.x & 3;
  const int rbase = rt * 32;
  __shared__ float Xs[32][33];    // [k][row], padded
  __shared__ float Ys[32][129];   // [k][col], padded
  __shared__ float xsq_s[32];
  __shared__ float ysq_s[128];
  const int tid = threadIdx.x;
  const int tr = tid >> 5;        // 0..7
  const int tc = tid & 31;        // 0..31
  float acc[4][4] = {{0.f,0.f,0.f,0.f},{0.f,0.f,0.f,0.f},
                     {0.f,0.f,0.f,0.f},{0.f,0.f,0.f,0.f}};
  float xsq[4] = {0.f,0.f,0.f,0.f};
  float ysq[4] = {0.f,0.f,0.f,0.f};
  const float* Xb = X + ((size_t)(b * NN + rbase)) * ND;
  const float* Yb = Y + ((size_t)(b * NN)) * ND;
  const int lrow = tid >> 3;          // 0..31
  const int lkk  = (tid & 7) << 2;    // 0,4,..,28

  for (int kb = 0; kb < ND; kb += 32) {
    __syncthreads();
    {
      float4 xv = *(const float4*)(Xb + (size_t)lrow * ND + kb + lkk);
      Xs[lkk + 0][lrow] = xv.x; Xs[lkk + 1][lrow] = xv.y;
      Xs[lkk + 2][lrow] = xv.z; Xs[lkk + 3][lrow] = xv.w;
    }
#pragma unroll
    for (int l = 0; l < 4; ++l) {
      int idx = tid + 256 * l;
      int col = idx >> 3;
      int kk  = (idx & 7) << 2;
      float4 yv = *(const float4*)(Yb + (size_t)col * ND + kb + kk);
      Ys[kk + 0][col] = yv.x; Ys[kk + 1][col] = yv.y;
      Ys[kk + 2][col] = yv.z; Ys[kk + 3][col] = yv.w;
    }
    __syncthreads();
#pragma unroll 4
    for (int kk = 0; kk < 32; ++kk) {
      float xv[4], yv[4];
#pragma unroll
      for (int ii = 0; ii < 4; ++ii) xv[ii] = Xs[kk][4 * tr + ii];
#pragma unroll
      for (int jj = 0; jj < 4; ++jj) yv[jj] = Ys[kk][tc + 32 * jj];
#pragma unroll
      for (int ii = 0; ii < 4; ++ii) xsq[ii] += xv[ii] * xv[ii];
#pragma unroll
      for (int jj = 0; jj < 4; ++jj) ysq[jj] += yv[jj] * yv[jj];
#pragma unroll
      for (int ii = 0; ii < 4; ++ii)
#pragma unroll
        for (int jj = 0; jj < 4; ++jj)
          acc[ii][jj] += xv[ii] * yv[jj];
    }
  }
  if (tc == 0) {
#pragma unroll
    for (int ii = 0; ii < 4; ++ii) xsq_s[4 * tr + ii] = xsq[ii];
  }
  if (tr == 0) {
#pragma unroll
    for (int jj = 0; jj < 4; ++jj) ysq_s[tc + 32 * jj] = ysq[jj];
  }
  __syncthreads();
#pragma unroll
  for (int ii = 0; ii < 4; ++ii) {
    int r = rbase + 4 * tr + ii;
    float xs = xsq_s[4 * tr + ii];
#pragma unroll
    for (int jj = 0; jj < 4; ++jj) {
      int c = tc + 32 * jj;
      float d2 = xs + ysq_s[c] - 2.0f * acc[ii][jj];
      cost[((size_t)(b * NN + r)) * NN + c] = sqrtf(fmaxf(d2, 0.0f));
    }
  }
}

// ---------------------------------------------------------------------------
// Cross-lane helpers (DPP-only; no ds_bpermute anywhere).
// ---------------------------------------------------------------------------
__device__ __forceinline__ unsigned umin2(unsigned a, unsigned b) { return a < b ? a : b; }
__device__ __forceinline__ unsigned umax2(unsigned a, unsigned b) { return a > b ? a : b; }

__device__ __forceinline__ unsigned wave_min_u32(unsigned x) {
  unsigned t;
  t = (unsigned)__builtin_amdgcn_update_dpp((int)x, (int)x, 0x111, 0xF, 0xF, false); x = umin2(x, t); // row_shr:1
  t = (unsigned)__builtin_amdgcn_update_dpp((int)x, (int)x, 0x112, 0xF, 0xF, false); x = umin2(x, t); // row_shr:2
  t = (unsigned)__builtin_amdgcn_update_dpp((int)x, (int)x, 0x114, 0xF, 0xF, false); x = umin2(x, t); // row_shr:4
  t = (unsigned)__builtin_amdgcn_update_dpp((int)x, (int)x, 0x118, 0xF, 0xF, false); x = umin2(x, t); // row_shr:8
  t = (unsigned)__builtin_amdgcn_update_dpp((int)x, (int)x, 0x142, 0xA, 0xF, false); x = umin2(x, t); // row_bcast:15
  t = (unsigned)__builtin_amdgcn_update_dpp((int)x, (int)x, 0x143, 0xC, 0xF, false); x = umin2(x, t); // row_bcast:31
  return (unsigned)__builtin_amdgcn_readlane((int)x, 63);
}

// dual (min, 2nd-min) reduction step; DPP ctrl/row_mask as template constants.
// Requires a <= b per lane on entry. Valid for the non-idempotent 2nd-min
// combine because the lane-63 path merges pairwise-disjoint windows:
// [48,63] + [32,47] (bcast15) + [0,31] (bcast31).
template <int CTRL, int RMASK>
__device__ __forceinline__ void min2_step(unsigned& a, unsigned& b) {
  unsigned ap = (unsigned)__builtin_amdgcn_update_dpp((int)a, (int)a, CTRL, RMASK, 0xF, false);
  unsigned bp = (unsigned)__builtin_amdgcn_update_dpp((int)b, (int)b, CTRL, RMASK, 0xF, false);
  unsigned hi = umax2(a, ap);
  a = umin2(a, ap);
  b = umin2(umin2(b, bp), hi);
}

__device__ __forceinline__ void wave_min2_u32(unsigned a, unsigned b,
                                              unsigned& m1k, unsigned& m2k) {
  min2_step<0x111, 0xF>(a, b);   // row_shr:1
  min2_step<0x112, 0xF>(a, b);   // row_shr:2
  min2_step<0x114, 0xF>(a, b);   // row_shr:4
  min2_step<0x118, 0xF>(a, b);   // row_shr:8
  min2_step<0x142, 0xA>(a, b);   // row_bcast:15
  min2_step<0x143, 0xC>(a, b);   // row_bcast:31
  m1k = (unsigned)__builtin_amdgcn_readlane((int)a, 63);
  m2k = (unsigned)__builtin_amdgcn_readlane((int)b, 63);
}

__device__ __forceinline__ double readlane_f64(double d, int lane) {
  int lo = __builtin_amdgcn_readlane(__double2loint(d), lane);
  int hi = __builtin_amdgcn_readlane(__double2hiint(d), lane);
  return __hiloint2double(hi, lo);
}

// ---------------------------------------------------------------------------
// Register-resident cost matrix: creg[2r] = cost[r][lane],
// creg[2r+1] = cost[r][lane+64]. Row index is WAVE-UNIFORM at every use, so
// a 128-case switch (scalar jump table, compile-time indices per case)
// replaces the ~120-cycle LDS row read with a ~20-cycle register lookup.
// NOTE: RL_CASE writes fixed-named locals rlC0/rlC1 declared inside the
// ROW_LOOKUP do-block (macro parameter substitution happens before nested
// expansion, so parameterizing the destination names does not work).
// ---------------------------------------------------------------------------
#define RL_CASE(R) case R: rlC0 = creg[2*(R)]; rlC1 = creg[2*(R)+1]; break;
#define RL_C4(B)  RL_CASE(B) RL_CASE((B)+1) RL_CASE((B)+2) RL_CASE((B)+3)
#define RL_C16(B) RL_C4(B) RL_C4((B)+4) RL_C4((B)+8) RL_C4((B)+12)
#define RL_C64(B) RL_C16(B) RL_C16((B)+16) RL_C16((B)+32) RL_C16((B)+48)
#define ROW_LOOKUP(RIDX, OUT0, OUT1)                               \
  do {                                                             \
    float rlC0 = 0.f, rlC1 = 0.f;                                  \
    switch (RIDX) {                                                \
      RL_C64(0) RL_C64(64)                                         \
      default: break;                                              \
    }                                                              \
    OUT0 = rlC0; OUT1 = rlC1;                                      \
  } while (0)

// ---------------------------------------------------------------------------
// Kernel B: JV / Hungarian, register-resident matrix version of the
// validated 533-us solver (round-9 math, byte-identical update rules).
// One wave per batch; lane owns cols {lane, lane+64}. Exact f64 state; f32
// monotone-bit keys for argmin. All loops hard-capped; control flow uniform.
// __launch_bounds__(64,1): allow ~310 VGPRs (256 matrix + state), no spill.
// ---------------------------------------------------------------------------
__global__ __launch_bounds__(64, 1) void hungarian_kernel(const float* __restrict__ cost,
                                                          int* __restrict__ cols) {
  const int b = blockIdx.x;
  const int lane = threadIdx.x;
  __shared__ int colrow[NN];         // init: argmin row per col; later: row-matched flags
  __shared__ int rwin[NN];           // init: winning col per row (or -1)
  __shared__ double u_row[NN + 1];   // u for rows (free/dispossessed roots)
  __shared__ int queue[4 * NN + 8];  // ARR work queue (1-based rows)
  __shared__ int qcnt[1];

  // ---- load cost matrix into registers (row-uniform access pattern) ----
  float creg[2 * NN];
  {
    const float* src = cost + (size_t)b * NN * NN;
#pragma unroll
    for (int r = 0; r < NN; ++r) {
      creg[2 * r]     = src[r * NN + lane];
      creg[2 * r + 1] = src[r * NN + lane + 64];
    }
  }
  // pin: block rematerialization-from-global of creg values
#pragma unroll
  for (int t = 0; t < 2 * NN; ++t) asm volatile("" : "+v"(creg[t]));

  for (int t = lane; t <= NN; t += 64) u_row[t] = 0.0;
  __syncthreads();

  // ---- column reduction: v[j] = min_i c[i][j], argmin row per col ----
  float cmin[2]; int cargr[2];
  {
    float mn0 = creg[0], mn1 = creg[1];
    int a0 = 0, a1 = 0;
#pragma unroll
    for (int r = 1; r < NN; ++r) {
      const float c0 = creg[2 * r], c1 = creg[2 * r + 1];
      if (c0 < mn0) { mn0 = c0; a0 = r; }
      if (c1 < mn1) { mn1 = c1; a1 = r; }
    }
    cmin[0] = mn0; cmin[1] = mn1; cargr[0] = a0; cargr[1] = a1;
    colrow[lane] = a0; colrow[lane + 64] = a1;
  }
  __syncthreads();
  // deterministic claim: row r matched to the SMALLEST col j with colrow[j]==r
  int rowwin[2] = {-1, -1};
  for (int j = 0; j < NN; ++j) {
    int rr = colrow[j];   // uniform broadcast read
#pragma unroll
    for (int k2 = 0; k2 < 2; ++k2) {
      if (rr == lane + 64 * k2 && rowwin[k2] < 0) rowwin[k2] = j;
    }
  }
#pragma unroll
  for (int k2 = 0; k2 < 2; ++k2) rwin[lane + 64 * k2] = rowwin[k2];
  const unsigned long long mask0 = __ballot(rowwin[0] >= 0);  // rows 0..63 matched
  const unsigned long long mask1 = __ballot(rowwin[1] >= 0);  // rows 64..127 matched
  __syncthreads();

  // per-column state (registers)
  int    p_[2];
  double pu_[2], v_[2];
#pragma unroll
  for (int k2 = 0; k2 < 2; ++k2) {
    const int j = lane + 64 * k2;
    const int r = cargr[k2];
    p_[k2]  = (rwin[r] == j) ? (r + 1) : 0;
    pu_[k2] = 0.0;
    v_[k2]  = (double)cmin[k2];
  }

  // ---- reduction transfer: for each greedy-matched row i with col j1:
  //      mu = min_{j != j1}(c - v); v[j1] -= mu; u_i (=pu at j1) = mu.
  for (int i = 1; i <= NN; ++i) {
    const bool matched = (i - 1) < 64 ? ((mask0 >> (i - 1)) & 1ull)
                                      : ((mask1 >> (i - 65)) & 1ull);
    if (!matched) continue;
    const int j1 = rwin[i - 1];          // uniform LDS read
    float c0r, c1r;
    ROW_LOOKUP(i - 1, c0r, c1r);
    double d0 = (double)c0r - v_[0];
    double d1 = (double)c1r - v_[1];
    if (lane == (j1 & 63)) { if (j1 >> 6) d1 = 1e300; else d0 = 1e300; }
    const double dmn = fmin(d0, d1);
    const unsigned k = __float_as_uint((float)dmn);  // 1e300 -> +inf bits, still monotone
    const unsigned mk = wave_min_u32(k);
    const unsigned long long bm = __ballot(k == mk);
    const int wl = (int)__ffsll(bm) - 1;
    const double mu = readlane_f64(dmn, wl);
    if (lane == (j1 & 63)) {
      if (j1 >> 6) { v_[1] -= mu; pu_[1] = mu; }
      else         { v_[0] -= mu; pu_[0] = mu; }
    }
  }

  // ---- augmenting row reduction (ARR), DPP dual-min version ----
  if (lane == 0) {
    int t = 0;
    for (int r = 1; r <= NN; ++r) {
      const bool m = (r - 1) < 64 ? ((mask0 >> (r - 1)) & 1ull)
                                  : ((mask1 >> (r - 65)) & 1ull);
      if (!m) queue[t++] = r;
    }
    qcnt[0] = t;
  }
  __syncthreads();
  {
    int head = 0, tail = qcnt[0];
    for (int pops = 0; head < tail && pops < 3 * NN; ++pops) {
      const int i = queue[head++];           // uniform broadcast read
      float c0r, c1r;
      ROW_LOOKUP(i - 1, c0r, c1r);
      const double d0 = (double)c0r - v_[0];
      const double d1 = (double)c1r - v_[1];
      double dmn, dmx; int jmn;
      if (d1 < d0) { dmn = d1; dmx = d0; jmn = lane + 64; }
      else         { dmn = d0; dmx = d1; jmn = lane; }
      const unsigned ka = __float_as_uint((float)dmn);
      const unsigned kb = __float_as_uint((float)dmx);
      unsigned m1k, m2k;
      wave_min2_u32(ka, kb, m1k, m2k);
      const unsigned long long bA = __ballot(ka == m1k);
      const int win = (int)__ffsll(bA) - 1;
      const double m1 = readlane_f64(dmn, win);
      const int j1 = __builtin_amdgcn_readlane(jmn, win);
      const unsigned long long bA2 = __ballot(ka == m2k) & ~(1ull << win);
      const unsigned long long bB2 = __ballot(kb == m2k);
      const int lA = bA2 ? (int)__ffsll(bA2) - 1 : 64;
      const int lB = bB2 ? (int)__ffsll(bB2) - 1 : 64;
      double m2 = (lA <= lB) ? readlane_f64(dmn, lA < 64 ? lA : 63)
                             : readlane_f64(dmx, lB < 64 ? lB : 63);
      m2 = fmax(m2, m1);
      // assign i -> j1; v[j1] -= (m2 - m1); u[i] = m2; dispossess k (if any)
      const int own = j1 & 63, hk = j1 >> 6;
      const int    psel  = hk ? p_[1]  : p_[0];
      const double pusel = hk ? pu_[1] : pu_[0];
      const int kk = __builtin_amdgcn_readlane(psel, own);
      const double oldpu = readlane_f64(pusel, own);
      if (lane == own) {
        if (hk) { v_[1] -= (m2 - m1); p_[1] = i; pu_[1] = m2; }
        else    { v_[0] -= (m2 - m1); p_[0] = i; pu_[0] = m2; }
      }
      if (lane == 0) {
        u_row[i] = m2;
        if (kk != 0) { u_row[kk] = oldpu; queue[tail] = kk; }
      }
      if (kk != 0) ++tail;
      __syncthreads();   // queue / u_row visibility for next pop
    }
  }
  __syncthreads();

  // ---- rebuild free-row masks after ARR (reuse colrow as flags) ----
  for (int t = lane; t < NN; t += 64) colrow[t] = 0;
  __syncthreads();
  if (p_[0] > 0) colrow[p_[0] - 1] = 1;
  if (p_[1] > 0) colrow[p_[1] - 1] = 1;
  __syncthreads();
  const unsigned long long fmask0 = __ballot(colrow[lane] == 0);       // free rows 1..64
  const unsigned long long fmask1 = __ballot(colrow[lane + 64] == 0);  // free rows 65..128

  const unsigned INFBITS = 0x7f800000u;  // +inf f32 bits

  // ---- augment each remaining free row with register Dijkstra ----
  for (int i = 1; i <= NN; ++i) {
    const bool freerow = (i - 1) < 64 ? ((fmask0 >> (i - 1)) & 1ull)
                                      : ((fmask1 >> (i - 65)) & 1ull);
    if (!freerow) continue;

    const double u_i = u_row[i];   // uniform broadcast read
    double D_[2]; int way_[2]; int used_[2] = {0, 0};
    {
      float c0r, c1r;
      ROW_LOOKUP(i - 1, c0r, c1r);
      D_[0] = (double)c0r - u_i - v_[0];  way_[0] = 0;
      D_[1] = (double)c1r - u_i - v_[1];  way_[1] = 0;
    }
    double Dfinal = 0.0; int jF = 1;
    for (int it = 0; it < NN + 2; ++it) {        // provable bound: <= NN+1
      // per-lane best of its 2 columns (exact f32 key, D>=0 clamped)
      const float pr0 = used_[0] ? __uint_as_float(INFBITS) : fmaxf((float)D_[0], 0.0f);
      const float pr1 = used_[1] ? __uint_as_float(INFBITS) : fmaxf((float)D_[1], 0.0f);
      const int   k2l = (pr1 < pr0) ? 1 : 0;
      const unsigned key = __float_as_uint(k2l ? pr1 : pr0);
      // wave argmin via DPP min + ballot + ffs (lowest lane on ties)
      const unsigned rmin = wave_min_u32(key);
      const unsigned long long wm = __ballot(key == rmin);
      const int winlane = (int)__ffsll(wm) - 1;
      // one meta readlane gives (i0, k2w)
      const int metal = ((k2l ? p_[1] : p_[0]) << 1) | k2l;
      const int meta = __builtin_amdgcn_readlane(metal, winlane);
      const int i0 = meta >> 1;
      const int k2w = meta & 1;
      const int bj = 1 + winlane + (k2w << 6);   // 1-based col
      const double bv = readlane_f64(k2l ? D_[1] : D_[0], winlane);
      if (i0 == 0) { Dfinal = bv; jF = bj; break; }   // free column reached
      // register row lookup (uniform index -> scalar jump table, ~20 cy)
      float c0r, c1r;
      ROW_LOOKUP((i0 - 1) & 127, c0r, c1r);
      const double u0 = readlane_f64(k2l ? pu_[1] : pu_[0], winlane);
      // mark used (static index) BEFORE relax so winner column is skipped
      if (lane == winlane) { if (k2w) used_[1] = 1; else used_[0] = 1; }
      const double base = bv - u0;
      if (!used_[0]) {
        const double cand = (double)c0r + base - v_[0];
        if (cand < D_[0]) { D_[0] = cand; way_[0] = bj; }
      }
      if (!used_[1]) {
        const double cand = (double)c1r + base - v_[1];
        if (cand < D_[1]) { D_[1] = cand; way_[1] = bj; }
      }
    }
    // potential updates (pre-augment matching semantics)
#pragma unroll
    for (int k2 = 0; k2 < 2; ++k2) {
      if (used_[k2]) {
        const double diff = Dfinal - D_[k2];
        v_[k2]  -= diff;
        pu_[k2] += diff;
      }
    }
    // augment along way (serial walk via readlanes; bounded; j uniform)
    int j = jF;
    for (int g = 0; g < NN + 2; ++g) {
      const int own = (j - 1) & 63;
      const int hk  = (j - 1) >> 6;
      const int wsel = hk ? way_[1] : way_[0];
      const int wj = __builtin_amdgcn_readlane(wsel, own);
      int pn; double pun;
      if (wj == 0) { pn = i; pun = u_i + Dfinal; }   // root row's new u
      else {
        const int o2 = (wj - 1) & 63, h2 = (wj - 1) >> 6;
        const int    psel2  = h2 ? p_[1]  : p_[0];
        const double pusel2 = h2 ? pu_[1] : pu_[0];
        pn  = __builtin_amdgcn_readlane(psel2, o2);
        pun = readlane_f64(pusel2, o2);
      }
      if (lane == own) {
        if (hk) { p_[1] = pn; pu_[1] = pun; }
        else    { p_[0] = pn; pu_[0] = pun; }
      }
      if (wj == 0) break;
      j = wj;
    }
  }

  // cols[b][p[j]-1] = j (0-based col)
#pragma unroll
  for (int k2 = 0; k2 < 2; ++k2) {
    const int r = p_[k2] - 1;
    if (r >= 0 && r < NN) cols[b * NN + r] = lane + 64 * k2;
  }
}

// ---------------------------------------------------------------------------
// Kernel C: gather outputs / probs by cols, write cols as float. (unchanged)
// ---------------------------------------------------------------------------
__global__ __launch_bounds__(256) void gather_kernel(const float* __restrict__ outs,
                                                     const float* __restrict__ probs,
                                                     const int* __restrict__ cols,
                                                     float* __restrict__ out) {
  const int bi = blockIdx.x;            // 0..8191
  const int b  = bi >> 7;
  const int col = cols[bi] & (NN - 1);  // clamp: garbage -> wrong answer, not fault
  const float4* src = (const float4*)(outs + ((size_t)(b * NN + col)) * ND);
  float4* dst = (float4*)(out + (size_t)bi * ND);
  const int t = threadIdx.x;
  dst[t]       = src[t];
  dst[t + 256] = src[t + 256];
  if (t == 0) {
    const size_t PROB_OFF = (size_t)NB * NN * ND;            // 16777216
    out[PROB_OFF + bi]        = probs[b * NN + col];
    out[PROB_OFF + 8192 + bi] = (float)(cols[bi] & (NN - 1));
  }
}

extern "C" void kernel_launch(void* const* d_in, const int* in_sizes, int n_in,
                              void* d_out, int out_size, void* d_ws, size_t ws_size,
                              hipStream_t stream) {
  const float* X = (const float*)d_in[0];   // inputs            [64,128,2048] f32
  const float* Y = (const float*)d_in[1];   // stacked_outputs   [64,128,2048] f32
  const float* P = (const float*)d_in[2];   // member_probs      [64,128,1]    f32
  float* out = (float*)d_out;

  float* cost = (float*)d_ws;                                   // 4 MB
  int* cols = (int*)((char*)d_ws + (size_t)NB * NN * NN * 4);   // 32 KB

  cost_kernel<<<dim3(NB * 4), dim3(256), 0, stream>>>(X, Y, cost);
  hungarian_kernel<<<dim3(NB), dim3(64), 0, stream>>>(cost, cols);
  gather_kernel<<<dim3(NB * NN), dim3(256), 0, stream>>>(Y, P, cols, out);
}

// Round 16
// 710.148 us; speedup vs baseline: 1.3109x; 1.3109x over previous
//
#include <hip/hip_runtime.h>

#define NB 64
#define NN 128
#define ND 2048

// ---------------------------------------------------------------------------
// Kernel A: cost[b][i][j] = sqrt(max(||x_i||^2 + ||y_j||^2 - 2 x_i.y_j, 0))
// v3: norms accumulated during STAGING (data touched once), inner loop is
// pure 4x4 FMA fed by two ds_read_b128 (X: 4 consecutive rows, half-wave
// broadcast; Y: 4 consecutive cols, full bank spread). Row strides padded
// to 16B multiples. float4 C-writes.
// ---------------------------------------------------------------------------
__global__ __launch_bounds__(256) void cost_kernel(const float* __restrict__ X,
                                                   const float* __restrict__ Y,
                                                   float* __restrict__ cost) {
  const int b  = blockIdx.x >> 2;
  const int rt = blockIdx.x & 3;
  const int rbase = rt * 32;
  __shared__ float Xs[32][36];    // [k][row], 36*4=144B rows (16B-aligned)
  __shared__ float Ys[32][132];   // [k][col], 132*4=528B rows (16B-aligned)
  __shared__ float Xp[32][8];     // X norm partials [row][k-slice]
  __shared__ float Yp[128][8];    // Y norm partials [col][k-slice]
  __shared__ float xsq_s[32];
  __shared__ float ysq_s[128];
  const int tid = threadIdx.x;
  const int tr = tid >> 5;        // 0..7  -> rows 4tr..4tr+3
  const int tc = tid & 31;        // 0..31 -> cols 4tc..4tc+3
  float acc[4][4] = {{0.f,0.f,0.f,0.f},{0.f,0.f,0.f,0.f},
                     {0.f,0.f,0.f,0.f},{0.f,0.f,0.f,0.f}};
  float nx = 0.f;                 // staged-X squares partial
  float ny[4] = {0.f,0.f,0.f,0.f};// staged-Y squares partials
  const float* Xb = X + ((size_t)(b * NN + rbase)) * ND;
  const float* Yb = Y + ((size_t)(b * NN)) * ND;
  const int srow = tid >> 3;          // 0..31 (X staging row)
  const int skk  = (tid & 7) << 2;    // 0,4,..,28 (k-slice)

  for (int kb = 0; kb < ND; kb += 32) {
    __syncthreads();
    {   // stage X tile: 32 rows x 32 k (1 float4/thread) + norm partial
      float4 v = *(const float4*)(Xb + (size_t)srow * ND + kb + skk);
      Xs[skk + 0][srow] = v.x; Xs[skk + 1][srow] = v.y;
      Xs[skk + 2][srow] = v.z; Xs[skk + 3][srow] = v.w;
      nx += v.x * v.x + v.y * v.y + v.z * v.z + v.w * v.w;
    }
#pragma unroll
    for (int l = 0; l < 4; ++l) {   // stage Y tile: 128 cols x 32 k + partials
      const int col = (tid >> 3) + 32 * l;
      float4 v = *(const float4*)(Yb + (size_t)col * ND + kb + skk);
      Ys[skk + 0][col] = v.x; Ys[skk + 1][col] = v.y;
      Ys[skk + 2][col] = v.z; Ys[skk + 3][col] = v.w;
      ny[l] += v.x * v.x + v.y * v.y + v.z * v.z + v.w * v.w;
    }
    __syncthreads();
#pragma unroll 8
    for (int kk = 0; kk < 32; ++kk) {
      const float4 xv4 = *(const float4*)&Xs[kk][4 * tr];
      const float4 yv4 = *(const float4*)&Ys[kk][4 * tc];
      const float xv[4] = {xv4.x, xv4.y, xv4.z, xv4.w};
      const float yv[4] = {yv4.x, yv4.y, yv4.z, yv4.w};
#pragma unroll
      for (int ii = 0; ii < 4; ++ii)
#pragma unroll
        for (int jj = 0; jj < 4; ++jj)
          acc[ii][jj] += xv[ii] * yv[jj];
    }
  }
  // ---- norm reduction: partials -> xsq_s / ysq_s ----
  Xp[srow][tid & 7] = nx;
#pragma unroll
  for (int l = 0; l < 4; ++l) Yp[(tid >> 3) + 32 * l][tid & 7] = ny[l];
  __syncthreads();
  if (tid < 32) {
    float s = 0.f;
#pragma unroll
    for (int q = 0; q < 8; ++q) s += Xp[tid][q];
    xsq_s[tid] = s;
  }
  if (tid < 128) {
    float s = 0.f;
#pragma unroll
    for (int q = 0; q < 8; ++q) s += Yp[tid][q];
    ysq_s[tid] = s;
  }
  __syncthreads();
  // ---- write: rows 4tr+ii, cols 4tc..4tc+3 (float4) ----
#pragma unroll
  for (int ii = 0; ii < 4; ++ii) {
    const int r = rbase + 4 * tr + ii;
    const float xs = xsq_s[4 * tr + ii];
    float4 o;
    o.x = sqrtf(fmaxf(xs + ysq_s[4 * tc + 0] - 2.0f * acc[ii][0], 0.0f));
    o.y = sqrtf(fmaxf(xs + ysq_s[4 * tc + 1] - 2.0f * acc[ii][1], 0.0f));
    o.z = sqrtf(fmaxf(xs + ysq_s[4 * tc + 2] - 2.0f * acc[ii][2], 0.0f));
    o.w = sqrtf(fmaxf(xs + ysq_s[4 * tc + 3] - 2.0f * acc[ii][3], 0.0f));
    *(float4*)&cost[((size_t)(b * NN + r)) * NN + 4 * tc] = o;
  }
}

// ---------------------------------------------------------------------------
// Cross-lane helpers (DPP-only; no ds_bpermute anywhere).
// ---------------------------------------------------------------------------
__device__ __forceinline__ unsigned umin2(unsigned a, unsigned b) { return a < b ? a : b; }
__device__ __forceinline__ unsigned umax2(unsigned a, unsigned b) { return a > b ? a : b; }

__device__ __forceinline__ unsigned wave_min_u32(unsigned x) {
  unsigned t;
  t = (unsigned)__builtin_amdgcn_update_dpp((int)x, (int)x, 0x111, 0xF, 0xF, false); x = umin2(x, t); // row_shr:1
  t = (unsigned)__builtin_amdgcn_update_dpp((int)x, (int)x, 0x112, 0xF, 0xF, false); x = umin2(x, t); // row_shr:2
  t = (unsigned)__builtin_amdgcn_update_dpp((int)x, (int)x, 0x114, 0xF, 0xF, false); x = umin2(x, t); // row_shr:4
  t = (unsigned)__builtin_amdgcn_update_dpp((int)x, (int)x, 0x118, 0xF, 0xF, false); x = umin2(x, t); // row_shr:8
  t = (unsigned)__builtin_amdgcn_update_dpp((int)x, (int)x, 0x142, 0xA, 0xF, false); x = umin2(x, t); // row_bcast:15
  t = (unsigned)__builtin_amdgcn_update_dpp((int)x, (int)x, 0x143, 0xC, 0xF, false); x = umin2(x, t); // row_bcast:31
  return (unsigned)__builtin_amdgcn_readlane((int)x, 63);
}

// dual (min, 2nd-min) reduction step; DPP ctrl/row_mask as template constants.
// Requires a <= b per lane on entry. Valid for the non-idempotent 2nd-min
// combine because the lane-63 path merges pairwise-disjoint windows:
// [48,63] + [32,47] (bcast15) + [0,31] (bcast31).
template <int CTRL, int RMASK>
__device__ __forceinline__ void min2_step(unsigned& a, unsigned& b) {
  unsigned ap = (unsigned)__builtin_amdgcn_update_dpp((int)a, (int)a, CTRL, RMASK, 0xF, false);
  unsigned bp = (unsigned)__builtin_amdgcn_update_dpp((int)b, (int)b, CTRL, RMASK, 0xF, false);
  unsigned hi = umax2(a, ap);
  a = umin2(a, ap);
  b = umin2(umin2(b, bp), hi);
}

__device__ __forceinline__ void wave_min2_u32(unsigned a, unsigned b,
                                              unsigned& m1k, unsigned& m2k) {
  min2_step<0x111, 0xF>(a, b);   // row_shr:1
  min2_step<0x112, 0xF>(a, b);   // row_shr:2
  min2_step<0x114, 0xF>(a, b);   // row_shr:4
  min2_step<0x118, 0xF>(a, b);   // row_shr:8
  min2_step<0x142, 0xA>(a, b);   // row_bcast:15
  min2_step<0x143, 0xC>(a, b);   // row_bcast:31
  m1k = (unsigned)__builtin_amdgcn_readlane((int)a, 63);
  m2k = (unsigned)__builtin_amdgcn_readlane((int)b, 63);
}

__device__ __forceinline__ double readlane_f64(double d, int lane) {
  int lo = __builtin_amdgcn_readlane(__double2loint(d), lane);
  int hi = __builtin_amdgcn_readlane(__double2hiint(d), lane);
  return __hiloint2double(hi, lo);
}

// ---------------------------------------------------------------------------
// Kernel B: JV / Hungarian — byte-identical to the thrice-validated 533-us
// version. Full JV init (column reduction + greedy claim + reduction
// transfer + ARR) then register-resident wave-synchronous Dijkstra.
// One wave per batch; lane owns cols {lane, lane+64}. Exact f64 state; f32
// monotone-bit keys for argmin. All loops hard-capped; control flow uniform.
// ---------------------------------------------------------------------------
__global__ __launch_bounds__(64) void hungarian_kernel(const float* __restrict__ cost,
                                                       int* __restrict__ cols) {
  const int b = blockIdx.x;
  const int lane = threadIdx.x;
  __shared__ float cst[NN * NN];     // 64 KB
  __shared__ int colrow[NN];         // init: argmin row per col; later: row-matched flags
  __shared__ int rwin[NN];           // init: winning col per row (or -1)
  __shared__ double u_row[NN + 1];   // u for rows (free/dispossessed roots)
  __shared__ int queue[4 * NN + 8];  // ARR work queue (1-based rows)
  __shared__ int qcnt[1];

  // load cost matrix into LDS (float4 coalesced)
  {
    const float4* src = (const float4*)(cost + (size_t)b * NN * NN);
    float4* dst = (float4*)cst;
    for (int t = lane; t < NN * NN / 4; t += 64) dst[t] = src[t];
  }
  for (int t = lane; t <= NN; t += 64) u_row[t] = 0.0;
  __syncthreads();

  // ---- column reduction: v[j] = min_i c[i][j], argmin row per col ----
  float cmin[2]; int cargr[2];
#pragma unroll
  for (int k2 = 0; k2 < 2; ++k2) {
    const int j = lane + 64 * k2;
    float mn = cst[j]; int ar = 0;
    for (int r = 1; r < NN; ++r) {
      float cr = cst[r * NN + j];
      if (cr < mn) { mn = cr; ar = r; }
    }
    cmin[k2] = mn; cargr[k2] = ar;
    colrow[j] = ar;
  }
  __syncthreads();
  // deterministic claim: row r matched to the SMALLEST col j with colrow[j]==r
  int rowwin[2] = {-1, -1};
  for (int j = 0; j < NN; ++j) {
    int rr = colrow[j];   // uniform broadcast read
#pragma unroll
    for (int k2 = 0; k2 < 2; ++k2) {
      if (rr == lane + 64 * k2 && rowwin[k2] < 0) rowwin[k2] = j;
    }
  }
#pragma unroll
  for (int k2 = 0; k2 < 2; ++k2) rwin[lane + 64 * k2] = rowwin[k2];
  const unsigned long long mask0 = __ballot(rowwin[0] >= 0);  // rows 0..63 matched
  const unsigned long long mask1 = __ballot(rowwin[1] >= 0);  // rows 64..127 matched
  __syncthreads();

  // per-column state (registers)
  int    p_[2];
  double pu_[2], v_[2];
#pragma unroll
  for (int k2 = 0; k2 < 2; ++k2) {
    const int j = lane + 64 * k2;
    const int r = cargr[k2];
    p_[k2]  = (rwin[r] == j) ? (r + 1) : 0;
    pu_[k2] = 0.0;
    v_[k2]  = (double)cmin[k2];
  }

  // ---- reduction transfer: for each greedy-matched row i with col j1:
  //      mu = min_{j != j1}(c - v); v[j1] -= mu; u_i (=pu at j1) = mu.
  for (int i = 1; i <= NN; ++i) {
    const bool matched = (i - 1) < 64 ? ((mask0 >> (i - 1)) & 1ull)
                                      : ((mask1 >> (i - 65)) & 1ull);
    if (!matched) continue;
    const int j1 = rwin[i - 1];          // uniform LDS read
    const float* crow = &cst[(i - 1) * NN];
    double d0 = (double)crow[lane]      - v_[0];
    double d1 = (double)crow[lane + 64] - v_[1];
    if (lane == (j1 & 63)) { if (j1 >> 6) d1 = 1e300; else d0 = 1e300; }
    const double dmn = fmin(d0, d1);
    const unsigned k = __float_as_uint((float)dmn);  // 1e300 -> +inf bits, still monotone
    const unsigned mk = wave_min_u32(k);
    const unsigned long long bm = __ballot(k == mk);
    const int wl = (int)__ffsll(bm) - 1;
    const double mu = readlane_f64(dmn, wl);
    if (lane == (j1 & 63)) {
      if (j1 >> 6) { v_[1] -= mu; pu_[1] = mu; }
      else         { v_[0] -= mu; pu_[0] = mu; }
    }
  }

  // ---- augmenting row reduction (ARR), DPP dual-min version ----
  if (lane == 0) {
    int t = 0;
    for (int r = 1; r <= NN; ++r) {
      const bool m = (r - 1) < 64 ? ((mask0 >> (r - 1)) & 1ull)
                                  : ((mask1 >> (r - 65)) & 1ull);
      if (!m) queue[t++] = r;
    }
    qcnt[0] = t;
  }
  __syncthreads();
  {
    int head = 0, tail = qcnt[0];
    for (int pops = 0; head < tail && pops < 3 * NN; ++pops) {
      const int i = queue[head++];           // uniform broadcast read
      const float* crow = cst + (i - 1) * NN;
      const double d0 = (double)crow[lane]      - v_[0];
      const double d1 = (double)crow[lane + 64] - v_[1];
      double dmn, dmx; int jmn;
      if (d1 < d0) { dmn = d1; dmx = d0; jmn = lane + 64; }
      else         { dmn = d0; dmx = d1; jmn = lane; }
      const unsigned ka = __float_as_uint((float)dmn);
      const unsigned kb = __float_as_uint((float)dmx);
      unsigned m1k, m2k;
      wave_min2_u32(ka, kb, m1k, m2k);
      const unsigned long long bA = __ballot(ka == m1k);
      const int win = (int)__ffsll(bA) - 1;
      const double m1 = readlane_f64(dmn, win);
      const int j1 = __builtin_amdgcn_readlane(jmn, win);
      const unsigned long long bA2 = __ballot(ka == m2k) & ~(1ull << win);
      const unsigned long long bB2 = __ballot(kb == m2k);
      const int lA = bA2 ? (int)__ffsll(bA2) - 1 : 64;
      const int lB = bB2 ? (int)__ffsll(bB2) - 1 : 64;
      double m2 = (lA <= lB) ? readlane_f64(dmn, lA < 64 ? lA : 63)
                             : readlane_f64(dmx, lB < 64 ? lB : 63);
      m2 = fmax(m2, m1);
      // assign i -> j1; v[j1] -= (m2 - m1); u[i] = m2; dispossess k (if any)
      const int own = j1 & 63, hk = j1 >> 6;
      const int    psel  = hk ? p_[1]  : p_[0];
      const double pusel = hk ? pu_[1] : pu_[0];
      const int kk = __builtin_amdgcn_readlane(psel, own);
      const double oldpu = readlane_f64(pusel, own);
      if (lane == own) {
        if (hk) { v_[1] -= (m2 - m1); p_[1] = i; pu_[1] = m2; }
        else    { v_[0] -= (m2 - m1); p_[0] = i; pu_[0] = m2; }
      }
      if (lane == 0) {
        u_row[i] = m2;
        if (kk != 0) { u_row[kk] = oldpu; queue[tail] = kk; }
      }
      if (kk != 0) ++tail;
      __syncthreads();   // queue / u_row visibility for next pop
    }
  }
  __syncthreads();

  // ---- rebuild free-row masks after ARR (reuse colrow as flags) ----
  for (int t = lane; t < NN; t += 64) colrow[t] = 0;
  __syncthreads();
  if (p_[0] > 0) colrow[p_[0] - 1] = 1;
  if (p_[1] > 0) colrow[p_[1] - 1] = 1;
  __syncthreads();
  const unsigned long long fmask0 = __ballot(colrow[lane] == 0);       // free rows 1..64
  const unsigned long long fmask1 = __ballot(colrow[lane + 64] == 0);  // free rows 65..128

  const unsigned INFBITS = 0x7f800000u;  // +inf f32 bits

  // ---- augment each remaining free row with register Dijkstra ----
  for (int i = 1; i <= NN; ++i) {
    const bool freerow = (i - 1) < 64 ? ((fmask0 >> (i - 1)) & 1ull)
                                      : ((fmask1 >> (i - 65)) & 1ull);
    if (!freerow) continue;

    const double u_i = u_row[i];   // uniform broadcast read
    double D_[2]; int way_[2]; int used_[2] = {0, 0};
    {
      const float* crow = &cst[(i - 1) * NN];
      D_[0] = (double)crow[lane]      - u_i - v_[0];  way_[0] = 0;
      D_[1] = (double)crow[lane + 64] - u_i - v_[1];  way_[1] = 0;
    }
    double Dfinal = 0.0; int jF = 1;
    for (int it = 0; it < NN + 2; ++it) {        // provable bound: <= NN+1
      // per-lane best of its 2 columns (exact f32 key, D>=0 clamped)
      const float pr0 = used_[0] ? __uint_as_float(INFBITS) : fmaxf((float)D_[0], 0.0f);
      const float pr1 = used_[1] ? __uint_as_float(INFBITS) : fmaxf((float)D_[1], 0.0f);
      const int   k2l = (pr1 < pr0) ? 1 : 0;
      const unsigned key = __float_as_uint(k2l ? pr1 : pr0);
      // wave argmin via DPP min + ballot + ffs (lowest lane on ties)
      const unsigned rmin = wave_min_u32(key);
      const unsigned long long wm = __ballot(key == rmin);
      const int winlane = (int)__ffsll(wm) - 1;
      // one meta readlane gives (i0, k2w) -> LDS row loads issue ASAP
      const int metal = ((k2l ? p_[1] : p_[0]) << 1) | k2l;
      const int meta = __builtin_amdgcn_readlane(metal, winlane);
      const int i0 = meta >> 1;
      const int k2w = meta & 1;
      const int bj = 1 + winlane + (k2w << 6);   // 1-based col
      const float* crow = &cst[((i0 - 1) & 127) * NN];
      const float c0 = crow[lane];          // in flight...
      const float c1 = crow[lane + 64];
      // ...overlapped with the exact-f64 readlanes
      const double bv = readlane_f64(k2l ? D_[1] : D_[0], winlane);
      if (i0 == 0) { Dfinal = bv; jF = bj; break; }   // free column reached
      const double u0 = readlane_f64(k2l ? pu_[1] : pu_[0], winlane);
      // mark used (static index) BEFORE relax so winner column is skipped
      if (lane == winlane) { if (k2w) used_[1] = 1; else used_[0] = 1; }
      const double base = bv - u0;
      if (!used_[0]) {
        const double cand = (double)c0 + base - v_[0];
        if (cand < D_[0]) { D_[0] = cand; way_[0] = bj; }
      }
      if (!used_[1]) {
        const double cand = (double)c1 + base - v_[1];
        if (cand < D_[1]) { D_[1] = cand; way_[1] = bj; }
      }
    }
    // potential updates (pre-augment matching semantics)
#pragma unroll
    for (int k2 = 0; k2 < 2; ++k2) {
      if (used_[k2]) {
        const double diff = Dfinal - D_[k2];
        v_[k2]  -= diff;
        pu_[k2] += diff;
      }
    }
    // augment along way (serial walk via readlanes; bounded; j uniform)
    int j = jF;
    for (int g = 0; g < NN + 2; ++g) {
      const int own = (j - 1) & 63;
      const int hk  = (j - 1) >> 6;
      const int wsel = hk ? way_[1] : way_[0];
      const int wj = __builtin_amdgcn_readlane(wsel, own);
      int pn; double pun;
      if (wj == 0) { pn = i; pun = u_i + Dfinal; }   // root row's new u
      else {
        const int o2 = (wj - 1) & 63, h2 = (wj - 1) >> 6;
        const int    psel2  = h2 ? p_[1]  : p_[0];
        const double pusel2 = h2 ? pu_[1] : pu_[0];
        pn  = __builtin_amdgcn_readlane(psel2, o2);
        pun = readlane_f64(pusel2, o2);
      }
      if (lane == own) {
        if (hk) { p_[1] = pn; pu_[1] = pun; }
        else    { p_[0] = pn; pu_[0] = pun; }
      }
      if (wj == 0) break;
      j = wj;
    }
  }

  // cols[b][p[j]-1] = j (0-based col)
#pragma unroll
  for (int k2 = 0; k2 < 2; ++k2) {
    const int r = p_[k2] - 1;
    if (r >= 0 && r < NN) cols[b * NN + r] = lane + 64 * k2;
  }
}

// ---------------------------------------------------------------------------
// Kernel C: gather outputs / probs by cols, write cols as float. (unchanged)
// ---------------------------------------------------------------------------
__global__ __launch_bounds__(256) void gather_kernel(const float* __restrict__ outs,
                                                     const float* __restrict__ probs,
                                                     const int* __restrict__ cols,
                                                     float* __restrict__ out) {
  const int bi = blockIdx.x;            // 0..8191
  const int b  = bi >> 7;
  const int col = cols[bi] & (NN - 1);  // clamp: garbage -> wrong answer, not fault
  const float4* src = (const float4*)(outs + ((size_t)(b * NN + col)) * ND);
  float4* dst = (float4*)(out + (size_t)bi * ND);
  const int t = threadIdx.x;
  dst[t]       = src[t];
  dst[t + 256] = src[t + 256];
  if (t == 0) {
    const size_t PROB_OFF = (size_t)NB * NN * ND;            // 16777216
    out[PROB_OFF + bi]        = probs[b * NN + col];
    out[PROB_OFF + 8192 + bi] = (float)(cols[bi] & (NN - 1));
  }
}

extern "C" void kernel_launch(void* const* d_in, const int* in_sizes, int n_in,
                              void* d_out, int out_size, void* d_ws, size_t ws_size,
                              hipStream_t stream) {
  const float* X = (const float*)d_in[0];   // inputs            [64,128,2048] f32
  const float* Y = (const float*)d_in[1];   // stacked_outputs   [64,128,2048] f32
  const float* P = (const float*)d_in[2];   // member_probs      [64,128,1]    f32
  float* out = (float*)d_out;

  float* cost = (float*)d_ws;                                   // 4 MB
  int* cols = (int*)((char*)d_ws + (size_t)NB * NN * NN * 4);   // 32 KB

  cost_kernel<<<dim3(NB * 4), dim3(256), 0, stream>>>(X, Y, cost);
  hungarian_kernel<<<dim3(NB), dim3(64), 0, stream>>>(cost, cols);
  gather_kernel<<<dim3(NB * NN), dim3(256), 0, stream>>>(Y, P, cols, out);
}

// Round 17
// 691.107 us; speedup vs baseline: 1.3470x; 1.0276x over previous
//
#include <hip/hip_runtime.h>

#define NB 64
#define NN 128
#define ND 2048

// ---------------------------------------------------------------------------
// Kernel A: cost[b][i][j] = sqrt(max(||x_i||^2 + ||y_j||^2 - 2 x_i.y_j, 0))
// Round-9 validated tiling (32-row x 128-col tiles, 4x4 per thread) with an
// XCD-aware block remap: same-batch blocks are spaced 64 apart in blockIdx,
// so under round-robin XCD dispatch (64 % 8 == 0) all 4 row-tiles of a batch
// land on the SAME XCD and share each 16 KB Y k-tile through that XCD's L2
// (Y HBM traffic ~4x lower).
// ---------------------------------------------------------------------------
__global__ __launch_bounds__(256) void cost_kernel(const float* __restrict__ X,
                                                   const float* __restrict__ Y,
                                                   float* __restrict__ cost) {
  const int b  = blockIdx.x & 63;       // batch   (XCD-swizzled mapping)
  const int rt = blockIdx.x >> 6;       // row-tile 0..3
  const int rbase = rt * 32;
  __shared__ float Xs[32][33];    // [k][row], padded
  __shared__ float Ys[32][129];   // [k][col], padded
  __shared__ float xsq_s[32];
  __shared__ float ysq_s[128];
  const int tid = threadIdx.x;
  const int tr = tid >> 5;        // 0..7
  const int tc = tid & 31;        // 0..31
  float acc[4][4] = {{0.f,0.f,0.f,0.f},{0.f,0.f,0.f,0.f},
                     {0.f,0.f,0.f,0.f},{0.f,0.f,0.f,0.f}};
  float xsq[4] = {0.f,0.f,0.f,0.f};
  float ysq[4] = {0.f,0.f,0.f,0.f};
  const float* Xb = X + ((size_t)(b * NN + rbase)) * ND;
  const float* Yb = Y + ((size_t)(b * NN)) * ND;
  const int lrow = tid >> 3;          // 0..31
  const int lkk  = (tid & 7) << 2;    // 0,4,..,28

  for (int kb = 0; kb < ND; kb += 32) {
    __syncthreads();
    {
      float4 xv = *(const float4*)(Xb + (size_t)lrow * ND + kb + lkk);
      Xs[lkk + 0][lrow] = xv.x; Xs[lkk + 1][lrow] = xv.y;
      Xs[lkk + 2][lrow] = xv.z; Xs[lkk + 3][lrow] = xv.w;
    }
#pragma unroll
    for (int l = 0; l < 4; ++l) {
      int idx = tid + 256 * l;
      int col = idx >> 3;
      int kk  = (idx & 7) << 2;
      float4 yv = *(const float4*)(Yb + (size_t)col * ND + kb + kk);
      Ys[kk + 0][col] = yv.x; Ys[kk + 1][col] = yv.y;
      Ys[kk + 2][col] = yv.z; Ys[kk + 3][col] = yv.w;
    }
    __syncthreads();
#pragma unroll 4
    for (int kk = 0; kk < 32; ++kk) {
      float xv[4], yv[4];
#pragma unroll
      for (int ii = 0; ii < 4; ++ii) xv[ii] = Xs[kk][4 * tr + ii];
#pragma unroll
      for (int jj = 0; jj < 4; ++jj) yv[jj] = Ys[kk][tc + 32 * jj];
#pragma unroll
      for (int ii = 0; ii < 4; ++ii) xsq[ii] += xv[ii] * xv[ii];
#pragma unroll
      for (int jj = 0; jj < 4; ++jj) ysq[jj] += yv[jj] * yv[jj];
#pragma unroll
      for (int ii = 0; ii < 4; ++ii)
#pragma unroll
        for (int jj = 0; jj < 4; ++jj)
          acc[ii][jj] += xv[ii] * yv[jj];
    }
  }
  if (tc == 0) {
#pragma unroll
    for (int ii = 0; ii < 4; ++ii) xsq_s[4 * tr + ii] = xsq[ii];
  }
  if (tr == 0) {
#pragma unroll
    for (int jj = 0; jj < 4; ++jj) ysq_s[tc + 32 * jj] = ysq[jj];
  }
  __syncthreads();
#pragma unroll
  for (int ii = 0; ii < 4; ++ii) {
    int r = rbase + 4 * tr + ii;
    float xs = xsq_s[4 * tr + ii];
#pragma unroll
    for (int jj = 0; jj < 4; ++jj) {
      int c = tc + 32 * jj;
      float d2 = xs + ysq_s[c] - 2.0f * acc[ii][jj];
      cost[((size_t)(b * NN + r)) * NN + c] = sqrtf(fmaxf(d2, 0.0f));
    }
  }
}

// ---------------------------------------------------------------------------
// Cross-lane helpers (DPP-only; no ds_bpermute anywhere).
// ---------------------------------------------------------------------------
__device__ __forceinline__ unsigned umin2(unsigned a, unsigned b) { return a < b ? a : b; }
__device__ __forceinline__ unsigned umax2(unsigned a, unsigned b) { return a > b ? a : b; }

__device__ __forceinline__ unsigned wave_min_u32(unsigned x) {
  unsigned t;
  t = (unsigned)__builtin_amdgcn_update_dpp((int)x, (int)x, 0x111, 0xF, 0xF, false); x = umin2(x, t); // row_shr:1
  t = (unsigned)__builtin_amdgcn_update_dpp((int)x, (int)x, 0x112, 0xF, 0xF, false); x = umin2(x, t); // row_shr:2
  t = (unsigned)__builtin_amdgcn_update_dpp((int)x, (int)x, 0x114, 0xF, 0xF, false); x = umin2(x, t); // row_shr:4
  t = (unsigned)__builtin_amdgcn_update_dpp((int)x, (int)x, 0x118, 0xF, 0xF, false); x = umin2(x, t); // row_shr:8
  t = (unsigned)__builtin_amdgcn_update_dpp((int)x, (int)x, 0x142, 0xA, 0xF, false); x = umin2(x, t); // row_bcast:15
  t = (unsigned)__builtin_amdgcn_update_dpp((int)x, (int)x, 0x143, 0xC, 0xF, false); x = umin2(x, t); // row_bcast:31
  return (unsigned)__builtin_amdgcn_readlane((int)x, 63);
}

// dual (min, 2nd-min) reduction step; DPP ctrl/row_mask as template constants.
// Requires a <= b per lane on entry. Valid for the non-idempotent 2nd-min
// combine because the lane-63 path merges pairwise-disjoint windows:
// [48,63] + [32,47] (bcast15) + [0,31] (bcast31).
template <int CTRL, int RMASK>
__device__ __forceinline__ void min2_step(unsigned& a, unsigned& b) {
  unsigned ap = (unsigned)__builtin_amdgcn_update_dpp((int)a, (int)a, CTRL, RMASK, 0xF, false);
  unsigned bp = (unsigned)__builtin_amdgcn_update_dpp((int)b, (int)b, CTRL, RMASK, 0xF, false);
  unsigned hi = umax2(a, ap);
  a = umin2(a, ap);
  b = umin2(umin2(b, bp), hi);
}

__device__ __forceinline__ void wave_min2_u32(unsigned a, unsigned b,
                                              unsigned& m1k, unsigned& m2k) {
  min2_step<0x111, 0xF>(a, b);   // row_shr:1
  min2_step<0x112, 0xF>(a, b);   // row_shr:2
  min2_step<0x114, 0xF>(a, b);   // row_shr:4
  min2_step<0x118, 0xF>(a, b);   // row_shr:8
  min2_step<0x142, 0xA>(a, b);   // row_bcast:15
  min2_step<0x143, 0xC>(a, b);   // row_bcast:31
  m1k = (unsigned)__builtin_amdgcn_readlane((int)a, 63);
  m2k = (unsigned)__builtin_amdgcn_readlane((int)b, 63);
}

__device__ __forceinline__ double readlane_f64(double d, int lane) {
  int lo = __builtin_amdgcn_readlane(__double2loint(d), lane);
  int hi = __builtin_amdgcn_readlane(__double2hiint(d), lane);
  return __hiloint2double(hi, lo);
}

// ---------------------------------------------------------------------------
// Kernel B: JV / Hungarian — byte-identical to the thrice-validated 533-us
// version. Full JV init (column reduction + greedy claim + reduction
// transfer + ARR) then register-resident wave-synchronous Dijkstra.
// One wave per batch; lane owns cols {lane, lane+64}. Exact f64 state; f32
// monotone-bit keys for argmin. All loops hard-capped; control flow uniform.
// ---------------------------------------------------------------------------
__global__ __launch_bounds__(64) void hungarian_kernel(const float* __restrict__ cost,
                                                       int* __restrict__ cols) {
  const int b = blockIdx.x;
  const int lane = threadIdx.x;
  __shared__ float cst[NN * NN];     // 64 KB
  __shared__ int colrow[NN];         // init: argmin row per col; later: row-matched flags
  __shared__ int rwin[NN];           // init: winning col per row (or -1)
  __shared__ double u_row[NN + 1];   // u for rows (free/dispossessed roots)
  __shared__ int queue[4 * NN + 8];  // ARR work queue (1-based rows)
  __shared__ int qcnt[1];

  // load cost matrix into LDS (float4 coalesced)
  {
    const float4* src = (const float4*)(cost + (size_t)b * NN * NN);
    float4* dst = (float4*)cst;
    for (int t = lane; t < NN * NN / 4; t += 64) dst[t] = src[t];
  }
  for (int t = lane; t <= NN; t += 64) u_row[t] = 0.0;
  __syncthreads();

  // ---- column reduction: v[j] = min_i c[i][j], argmin row per col ----
  float cmin[2]; int cargr[2];
#pragma unroll
  for (int k2 = 0; k2 < 2; ++k2) {
    const int j = lane + 64 * k2;
    float mn = cst[j]; int ar = 0;
    for (int r = 1; r < NN; ++r) {
      float cr = cst[r * NN + j];
      if (cr < mn) { mn = cr; ar = r; }
    }
    cmin[k2] = mn; cargr[k2] = ar;
    colrow[j] = ar;
  }
  __syncthreads();
  // deterministic claim: row r matched to the SMALLEST col j with colrow[j]==r
  int rowwin[2] = {-1, -1};
  for (int j = 0; j < NN; ++j) {
    int rr = colrow[j];   // uniform broadcast read
#pragma unroll
    for (int k2 = 0; k2 < 2; ++k2) {
      if (rr == lane + 64 * k2 && rowwin[k2] < 0) rowwin[k2] = j;
    }
  }
#pragma unroll
  for (int k2 = 0; k2 < 2; ++k2) rwin[lane + 64 * k2] = rowwin[k2];
  const unsigned long long mask0 = __ballot(rowwin[0] >= 0);  // rows 0..63 matched
  const unsigned long long mask1 = __ballot(rowwin[1] >= 0);  // rows 64..127 matched
  __syncthreads();

  // per-column state (registers)
  int    p_[2];
  double pu_[2], v_[2];
#pragma unroll
  for (int k2 = 0; k2 < 2; ++k2) {
    const int j = lane + 64 * k2;
    const int r = cargr[k2];
    p_[k2]  = (rwin[r] == j) ? (r + 1) : 0;
    pu_[k2] = 0.0;
    v_[k2]  = (double)cmin[k2];
  }

  // ---- reduction transfer: for each greedy-matched row i with col j1:
  //      mu = min_{j != j1}(c - v); v[j1] -= mu; u_i (=pu at j1) = mu.
  for (int i = 1; i <= NN; ++i) {
    const bool matched = (i - 1) < 64 ? ((mask0 >> (i - 1)) & 1ull)
                                      : ((mask1 >> (i - 65)) & 1ull);
    if (!matched) continue;
    const int j1 = rwin[i - 1];          // uniform LDS read
    const float* crow = &cst[(i - 1) * NN];
    double d0 = (double)crow[lane]      - v_[0];
    double d1 = (double)crow[lane + 64] - v_[1];
    if (lane == (j1 & 63)) { if (j1 >> 6) d1 = 1e300; else d0 = 1e300; }
    const double dmn = fmin(d0, d1);
    const unsigned k = __float_as_uint((float)dmn);  // 1e300 -> +inf bits, still monotone
    const unsigned mk = wave_min_u32(k);
    const unsigned long long bm = __ballot(k == mk);
    const int wl = (int)__ffsll(bm) - 1;
    const double mu = readlane_f64(dmn, wl);
    if (lane == (j1 & 63)) {
      if (j1 >> 6) { v_[1] -= mu; pu_[1] = mu; }
      else         { v_[0] -= mu; pu_[0] = mu; }
    }
  }

  // ---- augmenting row reduction (ARR), DPP dual-min version ----
  if (lane == 0) {
    int t = 0;
    for (int r = 1; r <= NN; ++r) {
      const bool m = (r - 1) < 64 ? ((mask0 >> (r - 1)) & 1ull)
                                  : ((mask1 >> (r - 65)) & 1ull);
      if (!m) queue[t++] = r;
    }
    qcnt[0] = t;
  }
  __syncthreads();
  {
    int head = 0, tail = qcnt[0];
    for (int pops = 0; head < tail && pops < 3 * NN; ++pops) {
      const int i = queue[head++];           // uniform broadcast read
      const float* crow = cst + (i - 1) * NN;
      const double d0 = (double)crow[lane]      - v_[0];
      const double d1 = (double)crow[lane + 64] - v_[1];
      double dmn, dmx; int jmn;
      if (d1 < d0) { dmn = d1; dmx = d0; jmn = lane + 64; }
      else         { dmn = d0; dmx = d1; jmn = lane; }
      const unsigned ka = __float_as_uint((float)dmn);
      const unsigned kb = __float_as_uint((float)dmx);
      unsigned m1k, m2k;
      wave_min2_u32(ka, kb, m1k, m2k);
      const unsigned long long bA = __ballot(ka == m1k);
      const int win = (int)__ffsll(bA) - 1;
      const double m1 = readlane_f64(dmn, win);
      const int j1 = __builtin_amdgcn_readlane(jmn, win);
      const unsigned long long bA2 = __ballot(ka == m2k) & ~(1ull << win);
      const unsigned long long bB2 = __ballot(kb == m2k);
      const int lA = bA2 ? (int)__ffsll(bA2) - 1 : 64;
      const int lB = bB2 ? (int)__ffsll(bB2) - 1 : 64;
      double m2 = (lA <= lB) ? readlane_f64(dmn, lA < 64 ? lA : 63)
                             : readlane_f64(dmx, lB < 64 ? lB : 63);
      m2 = fmax(m2, m1);
      // assign i -> j1; v[j1] -= (m2 - m1); u[i] = m2; dispossess k (if any)
      const int own = j1 & 63, hk = j1 >> 6;
      const int    psel  = hk ? p_[1]  : p_[0];
      const double pusel = hk ? pu_[1] : pu_[0];
      const int kk = __builtin_amdgcn_readlane(psel, own);
      const double oldpu = readlane_f64(pusel, own);
      if (lane == own) {
        if (hk) { v_[1] -= (m2 - m1); p_[1] = i; pu_[1] = m2; }
        else    { v_[0] -= (m2 - m1); p_[0] = i; pu_[0] = m2; }
      }
      if (lane == 0) {
        u_row[i] = m2;
        if (kk != 0) { u_row[kk] = oldpu; queue[tail] = kk; }
      }
      if (kk != 0) ++tail;
      __syncthreads();   // queue / u_row visibility for next pop
    }
  }
  __syncthreads();

  // ---- rebuild free-row masks after ARR (reuse colrow as flags) ----
  for (int t = lane; t < NN; t += 64) colrow[t] = 0;
  __syncthreads();
  if (p_[0] > 0) colrow[p_[0] - 1] = 1;
  if (p_[1] > 0) colrow[p_[1] - 1] = 1;
  __syncthreads();
  const unsigned long long fmask0 = __ballot(colrow[lane] == 0);       // free rows 1..64
  const unsigned long long fmask1 = __ballot(colrow[lane + 64] == 0);  // free rows 65..128

  const unsigned INFBITS = 0x7f800000u;  // +inf f32 bits

  // ---- augment each remaining free row with register Dijkstra ----
  for (int i = 1; i <= NN; ++i) {
    const bool freerow = (i - 1) < 64 ? ((fmask0 >> (i - 1)) & 1ull)
                                      : ((fmask1 >> (i - 65)) & 1ull);
    if (!freerow) continue;

    const double u_i = u_row[i];   // uniform broadcast read
    double D_[2]; int way_[2]; int used_[2] = {0, 0};
    {
      const float* crow = &cst[(i - 1) * NN];
      D_[0] = (double)crow[lane]      - u_i - v_[0];  way_[0] = 0;
      D_[1] = (double)crow[lane + 64] - u_i - v_[1];  way_[1] = 0;
    }
    double Dfinal = 0.0; int jF = 1;
    for (int it = 0; it < NN + 2; ++it) {        // provable bound: <= NN+1
      // per-lane best of its 2 columns (exact f32 key, D>=0 clamped)
      const float pr0 = used_[0] ? __uint_as_float(INFBITS) : fmaxf((float)D_[0], 0.0f);
      const float pr1 = used_[1] ? __uint_as_float(INFBITS) : fmaxf((float)D_[1], 0.0f);
      const int   k2l = (pr1 < pr0) ? 1 : 0;
      const unsigned key = __float_as_uint(k2l ? pr1 : pr0);
      // wave argmin via DPP min + ballot + ffs (lowest lane on ties)
      const unsigned rmin = wave_min_u32(key);
      const unsigned long long wm = __ballot(key == rmin);
      const int winlane = (int)__ffsll(wm) - 1;
      // one meta readlane gives (i0, k2w) -> LDS row loads issue ASAP
      const int metal = ((k2l ? p_[1] : p_[0]) << 1) | k2l;
      const int meta = __builtin_amdgcn_readlane(metal, winlane);
      const int i0 = meta >> 1;
      const int k2w = meta & 1;
      const int bj = 1 + winlane + (k2w << 6);   // 1-based col
      const float* crow = &cst[((i0 - 1) & 127) * NN];
      const float c0 = crow[lane];          // in flight...
      const float c1 = crow[lane + 64];
      // ...overlapped with the exact-f64 readlanes
      const double bv = readlane_f64(k2l ? D_[1] : D_[0], winlane);
      if (i0 == 0) { Dfinal = bv; jF = bj; break; }   // free column reached
      const double u0 = readlane_f64(k2l ? pu_[1] : pu_[0], winlane);
      // mark used (static index) BEFORE relax so winner column is skipped
      if (lane == winlane) { if (k2w) used_[1] = 1; else used_[0] = 1; }
      const double base = bv - u0;
      if (!used_[0]) {
        const double cand = (double)c0 + base - v_[0];
        if (cand < D_[0]) { D_[0] = cand; way_[0] = bj; }
      }
      if (!used_[1]) {
        const double cand = (double)c1 + base - v_[1];
        if (cand < D_[1]) { D_[1] = cand; way_[1] = bj; }
      }
    }
    // potential updates (pre-augment matching semantics)
#pragma unroll
    for (int k2 = 0; k2 < 2; ++k2) {
      if (used_[k2]) {
        const double diff = Dfinal - D_[k2];
        v_[k2]  -= diff;
        pu_[k2] += diff;
      }
    }
    // augment along way (serial walk via readlanes; bounded; j uniform)
    int j = jF;
    for (int g = 0; g < NN + 2; ++g) {
      const int own = (j - 1) & 63;
      const int hk  = (j - 1) >> 6;
      const int wsel = hk ? way_[1] : way_[0];
      const int wj = __builtin_amdgcn_readlane(wsel, own);
      int pn; double pun;
      if (wj == 0) { pn = i; pun = u_i + Dfinal; }   // root row's new u
      else {
        const int o2 = (wj - 1) & 63, h2 = (wj - 1) >> 6;
        const int    psel2  = h2 ? p_[1]  : p_[0];
        const double pusel2 = h2 ? pu_[1] : pu_[0];
        pn  = __builtin_amdgcn_readlane(psel2, o2);
        pun = readlane_f64(pusel2, o2);
      }
      if (lane == own) {
        if (hk) { p_[1] = pn; pu_[1] = pun; }
        else    { p_[0] = pn; pu_[0] = pun; }
      }
      if (wj == 0) break;
      j = wj;
    }
  }

  // cols[b][p[j]-1] = j (0-based col)
#pragma unroll
  for (int k2 = 0; k2 < 2; ++k2) {
    const int r = p_[k2] - 1;
    if (r >= 0 && r < NN) cols[b * NN + r] = lane + 64 * k2;
  }
}

// ---------------------------------------------------------------------------
// Kernel C: gather outputs / probs by cols, write cols as float. (unchanged)
// ---------------------------------------------------------------------------
__global__ __launch_bounds__(256) void gather_kernel(const float* __restrict__ outs,
                                                     const float* __restrict__ probs,
                                                     const int* __restrict__ cols,
                                                     float* __restrict__ out) {
  const int bi = blockIdx.x;            // 0..8191
  const int b  = bi >> 7;
  const int col = cols[bi] & (NN - 1);  // clamp: garbage -> wrong answer, not fault
  const float4* src = (const float4*)(outs + ((size_t)(b * NN + col)) * ND);
  float4* dst = (float4*)(out + (size_t)bi * ND);
  const int t = threadIdx.x;
  dst[t]       = src[t];
  dst[t + 256] = src[t + 256];
  if (t == 0) {
    const size_t PROB_OFF = (size_t)NB * NN * ND;            // 16777216
    out[PROB_OFF + bi]        = probs[b * NN + col];
    out[PROB_OFF + 8192 + bi] = (float)(cols[bi] & (NN - 1));
  }
}

extern "C" void kernel_launch(void* const* d_in, const int* in_sizes, int n_in,
                              void* d_out, int out_size, void* d_ws, size_t ws_size,
                              hipStream_t stream) {
  const float* X = (const float*)d_in[0];   // inputs            [64,128,2048] f32
  const float* Y = (const float*)d_in[1];   // stacked_outputs   [64,128,2048] f32
  const float* P = (const float*)d_in[2];   // member_probs      [64,128,1]    f32
  float* out = (float*)d_out;

  float* cost = (float*)d_ws;                                   // 4 MB
  int* cols = (int*)((char*)d_ws + (size_t)NB * NN * NN * 4);   // 32 KB

  cost_kernel<<<dim3(NB * 4), dim3(256), 0, stream>>>(X, Y, cost);
  hungarian_kernel<<<dim3(NB), dim3(64), 0, stream>>>(cost, cols);
  gather_kernel<<<dim3(NB * NN), dim3(256), 0, stream>>>(Y, P, cols, out);
}